// Round 3
// baseline (296.054 us; speedup 1.0000x reference)
//
#include <hip/hip_runtime.h>

typedef float floatx2 __attribute__((ext_vector_type(2)));

#define B_  128
#define T_  30
#define N_  10000
#define M_  5000
#define K_  10
#define OBS_W_ 50
#define EPS_ 1e-6f
#define LOG2F_ 0.69314718056f
#define BT_  3840              // unpadded rows (b*30 + t)
#define CHUNK_ 100             // chk segments per y-block (25 per wave) — known-good
#define SEGW_  (CHUNK_ / 4)    // segments per wave
#define NCHK_ (M_/CHUNK_)      // 50; blockIdx.y==50 handles obs
#define NB_ 10                 // max distinct b spanned by 256 rows
#define GX_ (BT_ / 256)                       // 15
#define NBLK_ ((NCHK_ + 1) * GX_)             // 765 blocks in K2
#define PART_OFF_ (40u * 1024u * 1024u)       // partials past tt (38.4 MB)
#define CNT_OFF_  (PART_OFF_ + 65536u)        // done-counter, own cache line

// tanh(x/2) = 1 - 2/(e^x+1), with HW rcp (1 ulp).
__device__ __forceinline__ float tanh_half(float x) {
    float r = __builtin_amdgcn_rcpf(__expf(x) + 1.f);
    return __builtin_fmaf(-2.f, r, 1.f);
}

// ---------------- Kernel 1: tanh -> fp8, transpose to tt[n][bt] -------------
// Tile 256 bt x 64 n. Register 4x4 transpose -> fp8 dwords staged in LDS ->
// per column a FULL 256B contiguous store. Also zero-inits K2's done-counter.
__global__ __launch_bounds__(256) void tanh_transpose_fp8(
    const float*   __restrict__ llrs,   // [BT, N]
    unsigned char* __restrict__ tt,     // [N, BT] fp8 e4m3
    unsigned int*  __restrict__ donecnt)
{
    if (blockIdx.x == 0 && blockIdx.y == 0 && threadIdx.x == 0)
        *donecnt = 0u;                  // visible to K2 via dispatch boundary

    __shared__ unsigned int lds[64][65];   // [row-quad][col], stride 65 dwords
    const int bt0 = blockIdx.x * 256;
    const int n0  = blockIdx.y * 64;
    const int tid = threadIdx.x;
    const int c4  = tid & 15;              // col-quad 0..15 (cols 4c4..4c4+3)
    const int r4b = tid >> 4;              // row-quad base 0..15

    #pragma unroll
    for (int it = 0; it < 4; ++it) {
        const int r4 = r4b + 16 * it;      // row-quad 0..63 (rows 4r4..4r4+3)
        if (n0 + 4 * c4 < N_) {            // whole float4 in-bounds when true
            float t[4][4];
            #pragma unroll
            for (int j = 0; j < 4; ++j) {
                float4 v = *(const float4*)(llrs +
                            (size_t)(bt0 + 4 * r4 + j) * N_ + n0 + 4 * c4);
                t[j][0] = tanh_half(v.x);
                t[j][1] = tanh_half(v.y);
                t[j][2] = tanh_half(v.z);
                t[j][3] = tanh_half(v.w);
            }
            #pragma unroll
            for (int k = 0; k < 4; ++k) {  // pack rows 4r4..4r4+3 of col 4c4+k
                int pk = __builtin_amdgcn_cvt_pk_fp8_f32(t[0][k], t[1][k], 0, false);
                pk     = __builtin_amdgcn_cvt_pk_fp8_f32(t[2][k], t[3][k], pk, true);
                lds[r4][4 * c4 + k] = (unsigned int)pk;
            }
        }
    }
    __syncthreads();

    // store: 16 threads per column; thread covers bt bytes [16w, 16w+16)
    const int w = tid & 15;
    #pragma unroll
    for (int it = 0; it < 4; ++it) {
        const int col = (tid >> 4) + 16 * it;   // 0..63
        if (n0 + col < N_) {
            uint4 d;
            d.x = lds[4 * w + 0][col];
            d.y = lds[4 * w + 1][col];
            d.z = lds[4 * w + 2][col];
            d.w = lds[4 * w + 3][col];
            *(uint4*)(tt + (size_t)(n0 + col) * BT_ + bt0 + 16 * w) = d;
        }
    }
}

// ---------------- Kernel 2: fp8 gather-product + BCE, fused finisher --------
__device__ __forceinline__ void cvt4(unsigned int qv, float* a) {
    floatx2 lo = __builtin_amdgcn_cvt_pk_f32_fp8((int)qv, false);
    floatx2 hi = __builtin_amdgcn_cvt_pk_f32_fp8((int)qv, true);
    a[0] = lo.x; a[1] = lo.y; a[2] = hi.x; a[3] = hi.y;
}

__device__ __forceinline__ void issue6(const int* __restrict__ sidx, int s,
                                       const unsigned char* __restrict__ col0,
                                       unsigned int* q) {
    #pragma unroll
    for (int t = 0; t < 6; ++t) {
        int it = sidx[s * 6 + t];
        q[t] = *(const unsigned int*)(col0 + (size_t)it * BT_);
    }
}

__device__ __forceinline__ float consume6(const unsigned int* q,
                                          float sgA, float sgB, int split) {
    float a[4], b4[4], p[4];
    cvt4(q[0], p);  cvt4(q[1], a);  cvt4(q[2], b4);
    #pragma unroll
    for (int j = 0; j < 4; ++j) p[j] *= a[j] * b4[j];
    cvt4(q[3], a);  cvt4(q[4], b4);
    #pragma unroll
    for (int j = 0; j < 4; ++j) p[j] *= a[j] * b4[j];
    cvt4(q[5], a);
    float local = 0.f;
    #pragma unroll
    for (int j = 0; j < 4; ++j) {
        float sg = (j >= split) ? sgB : sgA;
        float sp = sg * p[j] * a[j];
        sp = fminf(fmaxf(sp, -1.f + EPS_), 1.f - EPS_);
        local += 1.0f - __log2f(1.f + sp);      // *ln2 folded at the end
    }
    return local;
}

__global__ __launch_bounds__(256) void gather_loss_fp8(
    const unsigned char* __restrict__ tt,         // [N, BT] fp8
    const int*           __restrict__ syndromes,  // [B, M]
    const int*           __restrict__ observables,// [B, K]
    const int*           __restrict__ chk_idx,    // [M*6]
    const int*           __restrict__ obs_idx,    // [K*50]
    float*               __restrict__ partials,   // [NBLK_]
    unsigned int*        __restrict__ donecnt,    // zeroed by K1
    float*               __restrict__ out,        // [out_size]
    int                  out_size)
{
    __shared__ int   sidx[CHUNK_ * 6];   // 2.4 KB
    __shared__ int   ssyn[NB_][CHUNK_];  // 4.0 KB
    __shared__ float red[4];
    __shared__ int   lastFlag;

    const int tid  = threadIdx.x;
    const int lane = tid & 63;
    const int wave = tid >> 6;
    const int r0   = blockIdx.x * 256 + lane * 4;   // 4 rows per lane
    const int bA   = r0 / 30;
    const int bB   = (r0 + 3) / 30;                 // bA or bA+1
    const int split= (bA + 1) * 30 - r0;            // rows j>=split are in bB
    const int b_lo = (blockIdx.x * 256) / 30;
    const unsigned char* col0 = tt + r0;            // lane's slice base
    const int y = blockIdx.y;
    float acc = 0.f;                                // in units of log2

    if (y < NCHK_) {
        const int m0 = y * CHUNK_;
        for (int i = tid; i < CHUNK_ * 6; i += 256)
            sidx[i] = chk_idx[m0 * 6 + i];
        for (int i = tid; i < NB_ * CHUNK_; i += 256) {
            int bi = i / CHUNK_, j = i - bi * CHUNK_;
            int b  = b_lo + bi; if (b > B_ - 1) b = B_ - 1;
            ((int*)ssyn)[i] = syndromes[(size_t)b * M_ + m0 + j];
        }
        __syncthreads();
        const int iA = bA - b_lo, iB = bB - b_lo;
        const int sBeg = wave * SEGW_;

        // software pipeline: issue s+1's gathers before consuming s
        unsigned int q[2][6];
        issue6(sidx, sBeg, col0, q[0]);
        #pragma unroll
        for (int k = 0; k < SEGW_; ++k) {       // cur index is compile-time
            const int s = sBeg + k;
            if (k + 1 < SEGW_) issue6(sidx, s + 1, col0, q[(k + 1) & 1]);
            float sgA = ssyn[iA][s] ? -1.f : 1.f;
            float sgB = ssyn[iB][s] ? -1.f : 1.f;
            acc += consume6(q[k & 1], sgA, sgB, split);
        }
    } else {
        // observable segments: K=10, width 50 (tiny) — direct global reads
        for (int k = wave; k < K_; k += 4) {
            const int* oi = obs_idx + k * OBS_W_;
            float p[4] = {1.f, 1.f, 1.f, 1.f};
            #pragma unroll 5
            for (int j2 = 0; j2 < OBS_W_; ++j2) {
                unsigned int qq = *(const unsigned int*)(col0 + (size_t)oi[j2] * BT_);
                float a[4];
                cvt4(qq, a);
                p[0] *= a[0]; p[1] *= a[1]; p[2] *= a[2]; p[3] *= a[3];
            }
            float sgA = observables[(size_t)bA * K_ + k] ? -1.f : 1.f;
            float sgB = observables[(size_t)bB * K_ + k] ? -1.f : 1.f;
            #pragma unroll
            for (int j = 0; j < 4; ++j) {
                float sg = (j >= split) ? sgB : sgA;
                float sp = sg * p[j];
                sp = fminf(fmaxf(sp, -1.f + EPS_), 1.f - EPS_);
                acc += 1.0f - __log2f(1.f + sp);
            }
        }
    }

    // block reduce: wave64 shuffle, then cross-wave via LDS
    #pragma unroll
    for (int off = 32; off > 0; off >>= 1)
        acc += __shfl_down(acc, off, 64);
    if (lane == 0) red[wave] = acc;
    __syncthreads();

    // fused finisher: release-store partial, count; last block reduces.
    if (tid == 0) {
        float bsum = red[0] + red[1] + red[2] + red[3];
        const int slot = y * GX_ + blockIdx.x;
        __hip_atomic_store(&partials[slot], bsum,
                           __ATOMIC_RELEASE, __HIP_MEMORY_SCOPE_AGENT);
        unsigned prev = __hip_atomic_fetch_add(donecnt, 1u,
                           __ATOMIC_ACQ_REL, __HIP_MEMORY_SCOPE_AGENT);
        lastFlag = (prev == NBLK_ - 1);
    }
    __syncthreads();
    if (lastFlag) {
        float s = 0.f;
        for (int i = tid; i < NBLK_; i += 256)
            s += __hip_atomic_load(&partials[i],
                                   __ATOMIC_ACQUIRE, __HIP_MEMORY_SCOPE_AGENT);
        #pragma unroll
        for (int off = 32; off > 0; off >>= 1)
            s += __shfl_down(s, off, 64);
        if (lane == 0) red[wave] = s;
        __syncthreads();
        if (tid == 0)
            out[0] = (red[0] + red[1] + red[2] + red[3])
                     * (0.5f * LOG2F_ / (float)BT_);
        // zero padding in the (poisoned) output buffer
        for (int i = tid + 1; i < out_size; i += 256) out[i] = 0.f;
    }
}

extern "C" void kernel_launch(void* const* d_in, const int* in_sizes, int n_in,
                              void* d_out, int out_size, void* d_ws, size_t ws_size,
                              hipStream_t stream) {
    const float* all_llrs    = (const float*)d_in[0];
    const int*   syndromes   = (const int*)d_in[1];
    const int*   observables = (const int*)d_in[2];
    const int*   chk_idx     = (const int*)d_in[3];
    // d_in[4] = chk_seg (implicit: fixed width 6)
    const int*   obs_idx     = (const int*)d_in[5];
    // d_in[6] = obs_seg (implicit: fixed width 50)
    float*         out = (float*)d_out;
    unsigned char* tt  = (unsigned char*)d_ws;   // N_*BT_ = 38.4 MB fp8
    float*        partials = (float*)((unsigned char*)d_ws + PART_OFF_);
    unsigned int* donecnt  = (unsigned int*)((unsigned char*)d_ws + CNT_OFF_);

    // Kernel 1: tanh -> fp8 transpose (also zero-inits donecnt)
    dim3 g1(GX_, (N_ + 63) / 64);        // 15 x 157
    tanh_transpose_fp8<<<g1, 256, 0, stream>>>(all_llrs, tt, donecnt);

    // Kernel 2: gather-product loss + fused final reduction
    dim3 g2(GX_, NCHK_ + 1);             // 15 x 51
    gather_loss_fp8<<<g2, 256, 0, stream>>>(
        tt, syndromes, observables, chk_idx, obs_idx,
        partials, donecnt, out, out_size);
}

// Round 4
// 264.185 us; speedup vs baseline: 1.1206x; 1.1206x over previous
//
#include <hip/hip_runtime.h>

typedef float floatx2 __attribute__((ext_vector_type(2)));

#define B_  128
#define T_  30
#define N_  10000
#define M_  5000
#define K_  10
#define OBS_W_ 50
#define EPS_ 1e-6f
#define LOG2F_ 0.69314718056f
#define BT_  3840              // unpadded rows (b*30 + t)
#define CHUNK_ 200             // chk segments per y-block (50 per wave)
#define SEGW_  (CHUNK_ / 4)    // segments per wave
#define NCHK_ (M_/CHUNK_)      // 25; blockIdx.y==25 handles obs
#define NB_ 10                 // max distinct b spanned by 256 rows
#define NPART_ ((NCHK_ + 1) * (BT_ / 256))   // 26*15 = 390 partial slots
#define PART_OFF_ (40u * 1024u * 1024u)      // partials live past tt (38.4 MB)

// tanh(x/2) = 1 - 2/(e^x+1), with HW rcp (1 ulp).
__device__ __forceinline__ float tanh_half(float x) {
    float r = __builtin_amdgcn_rcpf(__expf(x) + 1.f);
    return __builtin_fmaf(-2.f, r, 1.f);
}

// ---------------- Kernel 1: tanh -> fp8, transpose to tt[n][bt] -------------
// Tile 256 bt x 64 n. Register 4x4 transpose -> fp8 dwords staged in LDS ->
// per column a FULL 256B contiguous store (2 whole 128B lines; no partial-line
// RMW, since 3840 = 15*256). Reads: 4x256B runs per dwordx4 wave-inst.
__global__ __launch_bounds__(256) void tanh_transpose_fp8(
    const float*   __restrict__ llrs,   // [BT, N]
    unsigned char* __restrict__ tt)     // [N, BT] fp8 e4m3
{
    __shared__ unsigned int lds[64][65];   // [row-quad][col], stride 65 dwords
    const int bt0 = blockIdx.x * 256;
    const int n0  = blockIdx.y * 64;
    const int tid = threadIdx.x;
    const int c4  = tid & 15;              // col-quad 0..15 (cols 4c4..4c4+3)
    const int r4b = tid >> 4;              // row-quad base 0..15

    #pragma unroll
    for (int it = 0; it < 4; ++it) {
        const int r4 = r4b + 16 * it;      // row-quad 0..63 (rows 4r4..4r4+3)
        if (n0 + 4 * c4 < N_) {            // whole float4 in-bounds when true
            float t[4][4];
            #pragma unroll
            for (int j = 0; j < 4; ++j) {
                float4 v = *(const float4*)(llrs +
                            (size_t)(bt0 + 4 * r4 + j) * N_ + n0 + 4 * c4);
                t[j][0] = tanh_half(v.x);
                t[j][1] = tanh_half(v.y);
                t[j][2] = tanh_half(v.z);
                t[j][3] = tanh_half(v.w);
            }
            #pragma unroll
            for (int k = 0; k < 4; ++k) {  // pack rows 4r4..4r4+3 of col 4c4+k
                int pk = __builtin_amdgcn_cvt_pk_fp8_f32(t[0][k], t[1][k], 0, false);
                pk     = __builtin_amdgcn_cvt_pk_fp8_f32(t[2][k], t[3][k], pk, true);
                lds[r4][4 * c4 + k] = (unsigned int)pk;
            }
        }
    }
    __syncthreads();

    // store: 16 threads per column; thread covers bt bytes [16w, 16w+16)
    const int w = tid & 15;
    #pragma unroll
    for (int it = 0; it < 4; ++it) {
        const int col = (tid >> 4) + 16 * it;   // 0..63
        if (n0 + col < N_) {
            uint4 d;
            d.x = lds[4 * w + 0][col];
            d.y = lds[4 * w + 1][col];
            d.z = lds[4 * w + 2][col];
            d.w = lds[4 * w + 3][col];
            *(uint4*)(tt + (size_t)(n0 + col) * BT_ + bt0 + 16 * w) = d;
        }
    }
}

// ---------------- Kernel 2: coalesced fp8 gather-product + BCE --------------
// Per-block partial STORED to a private slot (no same-address atomics).
// CHUNK 200: half the blocks of round-2's 100 — halves per-block overhead.
__device__ __forceinline__ void cvt4(unsigned int qv, float* a) {
    floatx2 lo = __builtin_amdgcn_cvt_pk_f32_fp8((int)qv, false);
    floatx2 hi = __builtin_amdgcn_cvt_pk_f32_fp8((int)qv, true);
    a[0] = lo.x; a[1] = lo.y; a[2] = hi.x; a[3] = hi.y;
}

__global__ __launch_bounds__(256) void gather_loss_fp8(
    const unsigned char* __restrict__ tt,         // [N, BT] fp8
    const int*           __restrict__ syndromes,  // [B, M]
    const int*           __restrict__ observables,// [B, K]
    const int*           __restrict__ chk_idx,    // [M*6]
    const int*           __restrict__ obs_idx,    // [K*50]
    float*               __restrict__ partials)   // [NPART_]
{
    __shared__ int   sidx[CHUNK_ * 6];   // 4.8 KB
    __shared__ int   ssyn[NB_][CHUNK_];  // 8.0 KB
    __shared__ float red[4];

    const int tid  = threadIdx.x;
    const int lane = tid & 63;
    const int wave = tid >> 6;
    const int r0   = blockIdx.x * 256 + lane * 4;   // 4 rows per lane
    const int bA   = r0 / 30;
    const int bB   = (r0 + 3) / 30;                 // bA or bA+1
    const int split= (bA + 1) * 30 - r0;            // rows j>=split are in bB
    const int b_lo = (blockIdx.x * 256) / 30;
    const unsigned char* col0 = tt + r0;            // lane's slice base
    const int y = blockIdx.y;
    float acc = 0.f;                                // in units of log2

    if (y < NCHK_) {
        const int m0 = y * CHUNK_;
        for (int i = tid; i < CHUNK_ * 6; i += 256)
            sidx[i] = chk_idx[m0 * 6 + i];
        for (int i = tid; i < NB_ * CHUNK_; i += 256) {
            int bi = i / CHUNK_, j = i - bi * CHUNK_;
            int b  = b_lo + bi; if (b > B_ - 1) b = B_ - 1;
            ((int*)ssyn)[i] = syndromes[(size_t)b * M_ + m0 + j];
        }
        __syncthreads();
        const int iA = bA - b_lo, iB = bB - b_lo;

        #pragma unroll 2
        for (int s = wave * SEGW_; s < wave * SEGW_ + SEGW_; ++s) {
            int i0 = sidx[s * 6 + 0], i1 = sidx[s * 6 + 1], i2 = sidx[s * 6 + 2];
            int i3 = sidx[s * 6 + 3], i4 = sidx[s * 6 + 4], i5 = sidx[s * 6 + 5];
            unsigned int q0 = *(const unsigned int*)(col0 + (size_t)i0 * BT_);
            unsigned int q1 = *(const unsigned int*)(col0 + (size_t)i1 * BT_);
            unsigned int q2 = *(const unsigned int*)(col0 + (size_t)i2 * BT_);
            unsigned int q3 = *(const unsigned int*)(col0 + (size_t)i3 * BT_);
            unsigned int q4 = *(const unsigned int*)(col0 + (size_t)i4 * BT_);
            unsigned int q5 = *(const unsigned int*)(col0 + (size_t)i5 * BT_);
            float a[4], b4[4], p[4];
            cvt4(q0, p);  cvt4(q1, a);  cvt4(q2, b4);
            #pragma unroll
            for (int j = 0; j < 4; ++j) p[j] *= a[j] * b4[j];
            cvt4(q3, a);  cvt4(q4, b4);
            #pragma unroll
            for (int j = 0; j < 4; ++j) p[j] *= a[j] * b4[j];
            cvt4(q5, a);
            float sgA = ssyn[iA][s] ? -1.f : 1.f;
            float sgB = ssyn[iB][s] ? -1.f : 1.f;
            #pragma unroll
            for (int j = 0; j < 4; ++j) {
                float sg = (j >= split) ? sgB : sgA;
                float sp = sg * p[j] * a[j];
                sp = fminf(fmaxf(sp, -1.f + EPS_), 1.f - EPS_);
                acc += 1.0f - __log2f(1.f + sp);    // *ln2 folded into finisher
            }
        }
    } else {
        // observable segments: K=10, width 50 (tiny) — direct global reads
        for (int k = wave; k < K_; k += 4) {
            const int* oi = obs_idx + k * OBS_W_;
            float p[4] = {1.f, 1.f, 1.f, 1.f};
            #pragma unroll 5
            for (int j2 = 0; j2 < OBS_W_; ++j2) {
                unsigned int qq = *(const unsigned int*)(col0 + (size_t)oi[j2] * BT_);
                float a[4];
                cvt4(qq, a);
                p[0] *= a[0]; p[1] *= a[1]; p[2] *= a[2]; p[3] *= a[3];
            }
            float sgA = observables[(size_t)bA * K_ + k] ? -1.f : 1.f;
            float sgB = observables[(size_t)bB * K_ + k] ? -1.f : 1.f;
            #pragma unroll
            for (int j = 0; j < 4; ++j) {
                float sg = (j >= split) ? sgB : sgA;
                float sp = sg * p[j];
                sp = fminf(fmaxf(sp, -1.f + EPS_), 1.f - EPS_);
                acc += 1.0f - __log2f(1.f + sp);
            }
        }
    }

    // block reduce: wave64 shuffle, then cross-wave via LDS; STORE partial
    #pragma unroll
    for (int off = 32; off > 0; off >>= 1)
        acc += __shfl_down(acc, off, 64);
    if (lane == 0) red[wave] = acc;
    __syncthreads();
    if (tid == 0)
        partials[y * (BT_ / 256) + blockIdx.x] = red[0] + red[1] + red[2] + red[3];
}

// ---------------- Kernel 3: tiny finisher — sum 390 partials ----------------
__global__ __launch_bounds__(256) void reduce_partials(
    const float* __restrict__ partials, float* __restrict__ out, int out_size)
{
    __shared__ float red[4];
    const int tid  = threadIdx.x;
    const int lane = tid & 63;
    const int wave = tid >> 6;
    float acc = 0.f;
    for (int i = tid; i < NPART_; i += 256) acc += partials[i];
    #pragma unroll
    for (int off = 32; off > 0; off >>= 1)
        acc += __shfl_down(acc, off, 64);
    if (lane == 0) red[wave] = acc;
    __syncthreads();
    if (tid == 0) {
        float s = red[0] + red[1] + red[2] + red[3];
        // BETA = 0.5 on both sums; mean over B*T rows; ln2 from log2 units.
        out[0] = s * (0.5f * LOG2F_ / (float)BT_);
    }
    // zero any padding in the output buffer (replaces the memset dispatch)
    for (int i = tid + 1; i < out_size; i += 256) out[i] = 0.f;
}

extern "C" void kernel_launch(void* const* d_in, const int* in_sizes, int n_in,
                              void* d_out, int out_size, void* d_ws, size_t ws_size,
                              hipStream_t stream) {
    const float* all_llrs    = (const float*)d_in[0];
    const int*   syndromes   = (const int*)d_in[1];
    const int*   observables = (const int*)d_in[2];
    const int*   chk_idx     = (const int*)d_in[3];
    // d_in[4] = chk_seg (implicit: fixed width 6)
    const int*   obs_idx     = (const int*)d_in[5];
    // d_in[6] = obs_seg (implicit: fixed width 50)
    float*         out = (float*)d_out;
    unsigned char* tt  = (unsigned char*)d_ws;   // N_*BT_ = 38.4 MB fp8
    float* partials = (float*)((unsigned char*)d_ws + PART_OFF_);

    // Kernel 1: tanh -> fp8 transpose (256-row tiles: full-line stores)
    dim3 g1(BT_ / 256, (N_ + 63) / 64);  // 15 x 157
    tanh_transpose_fp8<<<g1, 256, 0, stream>>>(all_llrs, tt);

    // Kernel 2: gather-product loss (y<25: chk chunks, y==25: obs)
    dim3 g2(BT_ / 256, NCHK_ + 1);       // 15 x 26
    gather_loss_fp8<<<g2, 256, 0, stream>>>(
        tt, syndromes, observables, chk_idx, obs_idx, partials);

    // Kernel 3: finisher — no same-address atomics, no memset dispatch
    reduce_partials<<<1, 256, 0, stream>>>(partials, out, out_size);
}